// Round 2
// baseline (435.802 us; speedup 1.0000x reference)
//
#include <hip/hip_runtime.h>
#include <stdint.h>

// ---------------------------------------------------------------------------
// OwnMultiHeadTransformer: B=4, S=2048, D=1024, H=16, HD=64, FF=4096
// fp32 I/O, bf16 MFMA internal.
//   0) cvt_all: fp32 inputs -> bf16 in d_ws
//   1) gemm256<2>: QKV projection (256x256 deep-pipe); V stored transposed
//   2) flash_attn: no-max exp2 softmax, S^T orientation (R3/R8)
//   3) gemm256<1>: FFN1 + relu (256x256 deep-pipe)
//   4) gemm128<0>: FFN2 -> d_out (fp32) [N=1024: only 128 blocks at 2562,
//      half the GPU would idle -> keep 128-tile kernel here]
// R8: flash_attn issue-early K/V staging + counted vmcnt + ones-MFMA rowsum
//     (97 -> 80.4 us measured; Mfma 30->41%).
// R9: gemm256: port QKV/FFN1 to 256x256 tile, BK=64, 8 waves, dbuf LDS
//     (128 KiB, 1 block/CU), with the SAME validated issue-early schedule:
//       compute buf[cur] -> s_barrier -> issue STAGE(t+2 -> buf[cur])
//       -> s_waitcnt vmcnt(8) [t+1 landed, t+2 in flight] -> s_barrier.
//     2x arithmetic intensity vs gemm128 + staging latency spans a full
//     compute phase instead of draining at every barrier (m97-structure
//     ceiling ~900 TF -> 256-structure ~1400+ TF). Fragment math, chunk
//     swizzle, and epilogues are reused verbatim from the verified gemm128.
// ---------------------------------------------------------------------------

typedef __attribute__((ext_vector_type(8))) short bf16x8;
typedef __attribute__((ext_vector_type(4))) float f32x4;

__device__ __forceinline__ float bf2f(unsigned short u) {
  union { float f; uint32_t i; } v; v.i = ((uint32_t)u) << 16; return v.f;
}
__device__ __forceinline__ unsigned short f2bf(float f) {
  union { float f; uint32_t i; } v; v.f = f;
  uint32_t i = v.i;
  return (unsigned short)((i + 0x7fffu + ((i >> 16) & 1u)) >> 16);  // RNE
}

#if __has_builtin(__builtin_amdgcn_exp2f)
#define EXP2(x) __builtin_amdgcn_exp2f(x)
#else
#define EXP2(x) __expf((x) * 0.6931471805599453f)
#endif

// pack two f32 -> two bf16 (RNE) in one instr; lo gets p0
__device__ __forceinline__ uint32_t cvtpk(float p0, float p1) {
  uint32_t r;
  asm("v_cvt_pk_bf16_f32 %0, %1, %2" : "=v"(r) : "v"(p0), "v"(p1));
  return r;
}

// async 16B global->LDS (wave-uniform base + lane*16 via tid-linear chunks)
__device__ __forceinline__ void gld16(const void* g, void* l) {
  __builtin_amdgcn_global_load_lds(
      (const __attribute__((address_space(1))) uint32_t*)(uintptr_t)g,
      (__attribute__((address_space(3))) uint32_t*)(uintptr_t)l, 16, 0, 0);
}

#define SCALE_Q 0.04508422002778011f  /* log2(e) / sqrt(D=1024) */

// ---- ws layout (bf16 element offsets) -------------------------------------
#define W1B          0
#define W2B    4194304
#define B1B    8388608
#define B2B    8392704
#define BQB    8393728
#define BKB    8394752
#define BVB    8395776
#define EMBB   8396800
#define WQB   16785408
#define WKB   17833984
#define WVB   18882560
#define QOFF  19931136
#define KOFF  28319744
#define VTOFF 36708352
#define HCOFF 45096960        /* peak 53485568 elems = 102 MiB */
#define HIDOFF 8396800        /* hid overlays dead emb/Wqkv regions */

// ---- 0) fp32 -> bf16 ------------------------------------------------------
__global__ void cvt_all(const float* __restrict__ emb, const float* __restrict__ Wq,
                        const float* __restrict__ bq,  const float* __restrict__ Wk,
                        const float* __restrict__ bk,  const float* __restrict__ Wv,
                        const float* __restrict__ bv,  const float* __restrict__ W1,
                        const float* __restrict__ b1,  const float* __restrict__ W2,
                        const float* __restrict__ b2,  unsigned short* __restrict__ ws) {
  const int i4 = blockIdx.x * 256 + threadIdx.x;
  if (i4 >= 4982784) return;
  const float* s; unsigned short* d; int base;
  if      (i4 < 2097152) { s = emb; d = ws + EMBB; base = 0; }
  else if (i4 < 2359296) { s = Wq;  d = ws + WQB;  base = 2097152; }
  else if (i4 < 2621440) { s = Wk;  d = ws + WKB;  base = 2359296; }
  else if (i4 < 2883584) { s = Wv;  d = ws + WVB;  base = 2621440; }
  else if (i4 < 3932160) { s = W1;  d = ws + W1B;  base = 2883584; }
  else if (i4 < 4980736) { s = W2;  d = ws + W2B;  base = 3932160; }
  else if (i4 < 4980992) { s = bq;  d = ws + BQB;  base = 4980736; }
  else if (i4 < 4981248) { s = bk;  d = ws + BKB;  base = 4980992; }
  else if (i4 < 4981504) { s = bv;  d = ws + BVB;  base = 4981248; }
  else if (i4 < 4982528) { s = b1;  d = ws + B1B;  base = 4981504; }
  else                   { s = b2;  d = ws + B2B;  base = 4982528; }
  const int j = i4 - base;
  const float4 v = ((const float4*)s)[j];
  ushort4 o;
  o.x = f2bf(v.x); o.y = f2bf(v.y); o.z = f2bf(v.z); o.w = f2bf(v.w);
  *(ushort4*)(d + (size_t)j * 4) = o;
}

// ---- GEMM 256x256 deep-pipe: MODE 1 = bias+relu, 2 = QKV routing ----------
// BK=64, 512 threads (8 waves as 2M x 4N), per-wave C = 128x64.
// LDS: A/B double-buffered 256x64 tiles = 128 KiB -> 1 block/CU; pipeline
// depth 2 with counted vmcnt keeps next tile's 8 loads in flight across
// barriers (flash-R8-validated schedule). Requires M = 8192 (32 row tiles),
// N % 256 == 0, K % 64 == 0.
template <int MODE>
__launch_bounds__(512, 2)
__global__ void gemm256(const unsigned short* __restrict__ A,
                        const unsigned short* __restrict__ W0,
                        const unsigned short* __restrict__ W1p,
                        const unsigned short* __restrict__ W2p,
                        const unsigned short* __restrict__ bias0,
                        const unsigned short* __restrict__ bias1,
                        const unsigned short* __restrict__ bias2,
                        unsigned short* __restrict__ out0,
                        unsigned short* __restrict__ out1,
                        unsigned short* __restrict__ out2,
                        float* __restrict__ foutp,
                        int N, int K) {
  __shared__ unsigned short At[2 * 256 * 64];
  __shared__ unsigned short Bt[2 * 256 * 64];
  const int tid  = threadIdx.x;
  const int wave = tid >> 6, lane = tid & 63;
  const int quad = lane >> 4, l15 = lane & 15;
  const int wm = wave >> 2, wn = wave & 3;  // 2 x 4 wave grid

  // XCD swizzle: xcd = lid&7 owns rowTiles == xcd (mod 8); 4 consecutive
  // blocks per xcd share a B col-panel.
  const int lid = blockIdx.x + blockIdx.y * gridDim.x;
  const int s_ = lid >> 3;
  const int rowBase = (((lid & 7) + ((s_ & 3) << 3)) << 8);  // rowTile*256
  const int colBase = ((s_ >> 2) << 8);                      // colTile*256

  const unsigned short* W = W0;
  const unsigned short* bias = bias0;
  int colW = colBase;
  if (MODE == 2) {
    const int which = colBase >> 10;
    if (which == 1) { W = W1p; bias = bias1; }
    if (which == 2) { W = W2p; bias = bias2; }
    colW = colBase & 1023;
  }

  // Staging: 2048 16B chunks/tile; phys chunk u = row*8 + cc holds logical
  // k-chunk ec = cc ^ (row&7). 8 consecutive lanes = one row's full 128B.
  const unsigned short* gA[4]; const unsigned short* gB[4];
  unsigned short *lA[4], *lB[4];
#pragma unroll
  for (int i = 0; i < 4; ++i) {
    const int u = tid + 512 * i;  // 0..2047
    const int r = u >> 3, e = (((u & 7) ^ (r & 7)) * 8);
    gA[i] = A + (size_t)(rowBase + r) * K + e;
    gB[i] = W + (size_t)(colW + r) * K + e;
    lA[i] = At + u * 8;
    lB[i] = Bt + u * 8;
  }

  // Fragment offsets (kk=0); kk=1 flips chunk bit 2 -> addr ^ 32 elems.
  int aoff[8], boff[4];
#pragma unroll
  for (int mt = 0; mt < 8; ++mt) {
    const int ra = wm * 128 + mt * 16 + l15;
    aoff[mt] = ra * 64 + ((quad ^ (ra & 7)) * 8);
  }
#pragma unroll
  for (int nt = 0; nt < 4; ++nt) {
    const int rb = wn * 64 + nt * 16 + l15;
    boff[nt] = rb * 64 + ((quad ^ (rb & 7)) * 8);
  }

  // prologue: tile0 -> buf0, tile1 -> buf1 (8 loads each, per wave)
#pragma unroll
  for (int i = 0; i < 4; ++i) { gld16(gA[i], lA[i]); gld16(gB[i], lB[i]); }
#pragma unroll
  for (int i = 0; i < 4; ++i) { gA[i] += 64; gB[i] += 64; }
#pragma unroll
  for (int i = 0; i < 4; ++i) { gld16(gA[i], lA[i] + 16384); gld16(gB[i], lB[i] + 16384); }
#pragma unroll
  for (int i = 0; i < 4; ++i) { gA[i] += 64; gB[i] += 64; }
  asm volatile("s_waitcnt vmcnt(8)" ::: "memory");  // tile0 landed
  __builtin_amdgcn_s_barrier();

  f32x4 acc[8][4] = {};
  const int T = K >> 6;
  for (int t = 0; t < T; ++t) {
    const int cur = t & 1;
    const unsigned short* Ab = At + (cur << 14);
    const unsigned short* Bb = Bt + (cur << 14);
#pragma unroll
    for (int kk = 0; kk < 2; ++kk) {
      const int kx = kk << 5;
      bf16x8 af[8], bfr[4];
#pragma unroll
      for (int mt = 0; mt < 8; ++mt) af[mt]  = *(const bf16x8*)(Ab + (aoff[mt] ^ kx));
#pragma unroll
      for (int nt = 0; nt < 4; ++nt) bfr[nt] = *(const bf16x8*)(Bb + (boff[nt] ^ kx));
      __builtin_amdgcn_s_setprio(1);
#pragma unroll
      for (int mt = 0; mt < 8; ++mt)
#pragma unroll
        for (int nt = 0; nt < 4; ++nt)
          acc[mt][nt] = __builtin_amdgcn_mfma_f32_16x16x32_bf16(
              af[mt], bfr[nt], acc[mt][nt], 0, 0, 0);
      __builtin_amdgcn_s_setprio(0);
    }
    if (t == T - 1) break;
    __builtin_amdgcn_s_barrier();        // all waves done reading buf[cur]
    if (t + 2 < T) {
      const int db = cur << 14;          // tile t+2 -> buf[cur]
#pragma unroll
      for (int i = 0; i < 4; ++i) { gld16(gA[i], lA[i] + db); gld16(gB[i], lB[i] + db); }
#pragma unroll
      for (int i = 0; i < 4; ++i) { gA[i] += 64; gB[i] += 64; }
      asm volatile("s_waitcnt vmcnt(8)" ::: "memory");  // t+1 landed, t+2 in flight
    } else {
      asm volatile("s_waitcnt vmcnt(0)" ::: "memory");  // t+1 (last tile) landed
    }
    __builtin_amdgcn_s_barrier();        // t+1 visible to all waves
  }

#pragma unroll
  for (int mt = 0; mt < 8; ++mt) {
    const int row = rowBase + wm * 128 + mt * 16 + quad * 4;
#pragma unroll
    for (int nt = 0; nt < 4; ++nt) {
      const int cIn = colW + wn * 64 + nt * 16 + l15;
      const float bv = bf2f(bias[cIn]);
      if (MODE == 2) {
        const int which = colBase >> 10;
        const int h = cIn >> 6, e = cIn & 63;
#pragma unroll
        for (int r = 0; r < 4; ++r) {
          const int tok = row + r;
          const int b = tok >> 11, s = tok & 2047;
          const float v = acc[mt][nt][r] + bv;
          const size_t bh = (size_t)(b * 16 + h);
          if (which == 0)      out0[(bh * 2048 + s) * 64 + e] = f2bf(v * SCALE_Q);
          else if (which == 1) out1[(bh * 2048 + s) * 64 + e] = f2bf(v);
          else                 out2[(bh * 64 + e) * 2048 + s] = f2bf(v);  // V^T
        }
      } else if (MODE == 1) {
#pragma unroll
        for (int r = 0; r < 4; ++r) {
          const float v = fmaxf(acc[mt][nt][r] + bv, 0.0f);
          out0[(size_t)(row + r) * N + cIn] = f2bf(v);
        }
      } else {
#pragma unroll
        for (int r = 0; r < 4; ++r)
          foutp[(size_t)(row + r) * N + cIn] = acc[mt][nt][r] + bv;
      }
    }
  }
}

// ---- GEMM 128x128 (kept for FFN2: N=1024 -> 512 blocks at this tile) ------
template <int MODE>
__launch_bounds__(256, 4)
__global__ void gemm128(const unsigned short* __restrict__ A,
                        const unsigned short* __restrict__ W0,
                        const unsigned short* __restrict__ W1p,
                        const unsigned short* __restrict__ W2p,
                        const unsigned short* __restrict__ bias0,
                        const unsigned short* __restrict__ bias1,
                        const unsigned short* __restrict__ bias2,
                        unsigned short* __restrict__ out0,
                        unsigned short* __restrict__ out1,
                        unsigned short* __restrict__ out2,
                        float* __restrict__ foutp,
                        int N, int K) {
  __shared__ unsigned short At[128 * 64];
  __shared__ unsigned short Bt[128 * 64];
  const int tid  = threadIdx.x;
  const int wave = tid >> 6, lane = tid & 63;
  const int quad = lane >> 4, l15 = lane & 15;

  const int lid = blockIdx.x + blockIdx.y * gridDim.x;
  const int s_ = lid >> 3;
  const int rowBase = (((lid & 7) + ((s_ & 7) << 3)) << 7);
  const int colBase = ((s_ >> 3) << 7);

  const unsigned short* W = W0;
  const unsigned short* bias = bias0;
  int colW = colBase;
  if (MODE == 2) {
    const int which = colBase >> 10;
    if (which == 1) { W = W1p; bias = bias1; }
    if (which == 2) { W = W2p; bias = bias2; }
    colW = colBase & 1023;
  }

  const unsigned short* gA[4]; const unsigned short* gB[4];
  unsigned short *lA[4], *lB[4];
#pragma unroll
  for (int i = 0; i < 4; ++i) {
    const int u = tid + 256 * i;
    const int r = u >> 3, e = (((u & 7) ^ (r & 7)) * 8);
    gA[i] = A + (size_t)(rowBase + r) * K + e;
    gB[i] = W + (size_t)(colW + r) * K + e;
    lA[i] = At + u * 8;
    lB[i] = Bt + u * 8;
  }

  const int wrow = (wave & 1) * 64, wcol = (wave >> 1) * 64;
  int aoff[2][4], boff[2][4];
#pragma unroll
  for (int kk = 0; kk < 2; ++kk)
#pragma unroll
    for (int t = 0; t < 4; ++t) {
      const int ra = wrow + t * 16 + l15;
      aoff[kk][t] = ra * 64 + (((quad + 4 * kk) ^ (ra & 7)) * 8);
      const int rb = wcol + t * 16 + l15;
      boff[kk][t] = rb * 64 + (((quad + 4 * kk) ^ (rb & 7)) * 8);
    }

  f32x4 acc[4][4] = {};
  for (int k0 = 0; k0 < K; k0 += 64) {
    __syncthreads();
#pragma unroll
    for (int i = 0; i < 4; ++i) { gld16(gA[i], lA[i]); gld16(gB[i], lB[i]); }
#pragma unroll
    for (int i = 0; i < 4; ++i) { gA[i] += 64; gB[i] += 64; }
    __syncthreads();
#pragma unroll
    for (int kk = 0; kk < 2; ++kk) {
      bf16x8 af[4], bfr[4];
#pragma unroll
      for (int t = 0; t < 4; ++t) af[t]  = *(const bf16x8*)(At + aoff[kk][t]);
#pragma unroll
      for (int t = 0; t < 4; ++t) bfr[t] = *(const bf16x8*)(Bt + boff[kk][t]);
#pragma unroll
      for (int mt = 0; mt < 4; ++mt)
#pragma unroll
        for (int nt = 0; nt < 4; ++nt)
          acc[mt][nt] = __builtin_amdgcn_mfma_f32_16x16x32_bf16(
              af[mt], bfr[nt], acc[mt][nt], 0, 0, 0);
    }
  }

#pragma unroll
  for (int mt = 0; mt < 4; ++mt) {
    const int row = rowBase + wrow + mt * 16 + quad * 4;
#pragma unroll
    for (int nt = 0; nt < 4; ++nt) {
      const int cIn = colW + wcol + nt * 16 + l15;
      const float bv = bf2f(bias[cIn]);
      if (MODE == 2) {
        const int which = colBase >> 10;
        const int h = cIn >> 6, e = cIn & 63;
#pragma unroll
        for (int r = 0; r < 4; ++r) {
          const int tok = row + r;
          const int b = tok >> 11, s = tok & 2047;
          const float v = acc[mt][nt][r] + bv;
          const size_t bh = (size_t)(b * 16 + h);
          if (which == 0)      out0[(bh * 2048 + s) * 64 + e] = f2bf(v * SCALE_Q);
          else if (which == 1) out1[(bh * 2048 + s) * 64 + e] = f2bf(v);
          else                 out2[(bh * 64 + e) * 2048 + s] = f2bf(v);  // V^T
        }
      } else if (MODE == 1) {
#pragma unroll
        for (int r = 0; r < 4; ++r) {
          const float v = fmaxf(acc[mt][nt][r] + bv, 0.0f);
          out0[(size_t)(row + r) * N + cIn] = f2bf(v);
        }
      } else {
#pragma unroll
        for (int r = 0; r < 4; ++r)
          foutp[(size_t)(row + r) * N + cIn] = acc[mt][nt][r] + bv;
      }
    }
  }
}

// ---- flash attention (R3/R8): S^T orientation, no-max exp2 softmax --------
// grid (16, 64): logical (q-block, b*16+h); XCD-swizzled.
// R8 schedule per iter (raw barriers, counted vmcnt):
//   a: issue K(it+1) -> Kt[buf^1]           (unconditional; garbage tile 32
//      lands in the never-read buffer and is drained at (e))
//   b: QK^T from Kt[buf] + softmax + P pack (per-wave LDS)
//   c: s_waitcnt vmcnt(2) [own V(it) landed; K(it+1) stays in flight]
//      s_barrier            [all waves' V(it) landed; Kt[buf] reads done]
//   d: PV + ones-MFMA row-sum l
//   e: s_waitcnt vmcnt(0) [own K(it+1) landed]
//      s_barrier            [all waves done reading Vs + all K(it+1) landed]
//   f: issue V(it+1) -> Vs  (skipped at it=31 so kernel ends with vmcnt=0)
__launch_bounds__(256, 4)
__global__ void flash_attn(const unsigned short* __restrict__ Q,
                           const unsigned short* __restrict__ Kg,
                           const unsigned short* __restrict__ Vt,
                           unsigned short* __restrict__ Hc) {
  __shared__ unsigned short Kt[2 * 64 * 64];  // K tile dbuf [t][e], chunk-swizzled
  __shared__ unsigned short Vs[64 * 64];      // V^T tile [e][t], chunk-swizzled
  __shared__ unsigned short Pl[4][32 * 64];   // per-wave P [q][t], chunk-swizzled
  const int tid  = threadIdx.x;
  const int wave = tid >> 6, lane = tid & 63;
  const int quad = lane >> 4, l15 = lane & 15;

  // XCD swizzle: 8 bh's per XCD, q-blocks iterated within -> KV hot in L2.
  const int lid = blockIdx.x + blockIdx.y * gridDim.x;
  const int s_ = lid >> 3;
  const int bh = (lid & 7) + ((s_ & 7) << 3);
  const int q0 = ((s_ >> 3) << 7) + wave * 32;

  const size_t base = (size_t)bh * (2048 * 64);
  const unsigned short* Qb = Q  + base;
  const unsigned short* Kb = Kg + base;
  const unsigned short* Vb = Vt + base;   // [64 e][2048 t]

  // Q fragments (MFMA B operand for S^T: n=q=l15, k=e=quad*8+j)
  bf16x8 qf[2][2];
#pragma unroll
  for (int qt = 0; qt < 2; ++qt) {
    const int q = q0 + qt * 16 + l15;
#pragma unroll
    for (int kk = 0; kk < 2; ++kk)
      qf[qt][kk] = *(const bf16x8*)(Qb + (size_t)q * 64 + kk * 32 + quad * 8);
  }

  // KV staging (8-elem chunk swizzle: ec = cc ^ (row&7); 8 lanes = one 128B row)
  const int u0 = tid, u1 = tid + 256;
  const int kr0 = u0 >> 3, kc0 = (((u0 & 7) ^ (kr0 & 7)) * 8);
  const int kr1 = u1 >> 3, kc1 = (((u1 & 7) ^ (kr1 & 7)) * 8);
  const unsigned short* gK0 = Kb + (size_t)kr0 * 64 + kc0;
  const unsigned short* gK1 = Kb + (size_t)kr1 * 64 + kc1;
  const unsigned short* gV0 = Vb + (size_t)kr0 * 2048 + kc0;
  const unsigned short* gV1 = Vb + (size_t)kr1 * 2048 + kc1;
  unsigned short* lK0 = Kt + u0 * 8;
  unsigned short* lK1 = Kt + u1 * 8;
  unsigned short* lV0 = Vs + u0 * 8;
  unsigned short* lV1 = Vs + u1 * 8;

  // prologue: tile 0 into Kt[0] / Vs, full drain
  gld16(gK0, lK0); gld16(gK1, lK1);
  gld16(gV0, lV0); gld16(gV1, lV1);
  gK0 += 4096; gK1 += 4096; gV0 += 64; gV1 += 64;
  __syncthreads();

  const short oneb = (short)0x3F80;  // bf16 1.0
  const bf16x8 ones = {oneb, oneb, oneb, oneb, oneb, oneb, oneb, oneb};
  f32x4 o[2][4] = {};
  f32x4 lacc[2] = {};
  unsigned short* Pw = Pl[wave];

  for (int it = 0; it < 32; ++it) {
    const int nb = ((it + 1) & 1) * 4096;
    // (a) prefetch next K tile into the other buffer
    gld16(gK0, lK0 + nb); gld16(gK1, lK1 + nb);
    gK0 += 4096; gK1 += 4096;

    const unsigned short* Kc = Kt + (it & 1) * 4096;

    // (b) S^T = K Q^T : C row = t_local = tt*16+quad*4+r, col = q = qt*16+l15
    f32x4 st[4][2] = {};
    __builtin_amdgcn_s_setprio(1);
#pragma unroll
    for (int tt = 0; tt < 4; ++tt) {
      const int t = tt * 16 + l15;
      const bf16x8 kf0 = *(const bf16x8*)(Kc + t * 64 + ((quad       ^ (t & 7)) * 8));
      const bf16x8 kf1 = *(const bf16x8*)(Kc + t * 64 + (((quad + 4) ^ (t & 7)) * 8));
#pragma unroll
      for (int qt = 0; qt < 2; ++qt) {
        st[tt][qt] = __builtin_amdgcn_mfma_f32_16x16x32_bf16(kf0, qf[qt][0], st[tt][qt], 0, 0, 0);
        st[tt][qt] = __builtin_amdgcn_mfma_f32_16x16x32_bf16(kf1, qf[qt][1], st[tt][qt], 0, 0, 0);
      }
    }
    __builtin_amdgcn_s_setprio(0);

    // p = exp2(s) (no max: scores bounded), pack -> P[q][t] LDS (per-wave)
#pragma unroll
    for (int tt = 0; tt < 4; ++tt) {
      const int tc = tt * 2 + (quad >> 1);
#pragma unroll
      for (int qt = 0; qt < 2; ++qt) {
        const float p0 = EXP2(st[tt][qt][0]);
        const float p1 = EXP2(st[tt][qt][1]);
        const float p2 = EXP2(st[tt][qt][2]);
        const float p3 = EXP2(st[tt][qt][3]);
        uint2 w;
        w.x = cvtpk(p0, p1);
        w.y = cvtpk(p2, p3);
        const int qrow = qt * 16 + l15;
        *(uint2*)(Pw + qrow * 64 + ((tc ^ (qrow & 7)) * 8) + (quad & 1) * 4) = w;
      }
    }

    // (c) own V(it) landed (K(it+1) stays in flight), then all-waves barrier
    asm volatile("s_waitcnt vmcnt(2)" ::: "memory");
    __builtin_amdgcn_s_barrier();

    // (d) O += P V ; l += P * 1  (same-wave LDS round-trip, lgkm-ordered)
    bf16x8 pf[2][2];
#pragma unroll
    for (int mt = 0; mt < 2; ++mt) {
      const int qq = mt * 16 + l15;
      pf[mt][0] = *(const bf16x8*)(Pw + qq * 64 + ((quad       ^ (qq & 7)) * 8));
      pf[mt][1] = *(const bf16x8*)(Pw + qq * 64 + (((quad + 4) ^ (qq & 7)) * 8));
    }
    __builtin_amdgcn_s_setprio(1);
#pragma unroll
    for (int nt = 0; nt < 4; ++nt) {
      const int e = nt * 16 + l15;
      const bf16x8 vf0 = *(const bf16x8*)(Vs + e * 64 + ((quad       ^ (e & 7)) * 8));
      const bf16x8 vf1 = *(const bf16x8*)(Vs + e * 64 + (((quad + 4) ^ (e & 7)) * 8));
#pragma unroll
      for (int mt = 0; mt < 2; ++mt) {
        o[mt][nt] = __builtin_amdgcn_mfma_f32_16x16x32_bf16(pf[mt][0], vf0, o[mt][nt], 0, 0, 0);
        o[mt][nt] = __builtin_amdgcn_mfma_f32_16x16x32_bf16(pf[mt][1], vf1, o[mt][nt], 0, 0, 0);
      }
    }
    // row-sum l: D[q][*] = sum_t P[q][t]; rows match o's C-layout rows.
#pragma unroll
    for (int mt = 0; mt < 2; ++mt) {
      lacc[mt] = __builtin_amdgcn_mfma_f32_16x16x32_bf16(pf[mt][0], ones, lacc[mt], 0, 0, 0);
      lacc[mt] = __builtin_amdgcn_mfma_f32_16x16x32_bf16(pf[mt][1], ones, lacc[mt], 0, 0, 0);
    }
    __builtin_amdgcn_s_setprio(0);

    // (e) own K(it+1) landed + all waves done reading Vs
    asm volatile("s_waitcnt vmcnt(0)" ::: "memory");
    __builtin_amdgcn_s_barrier();

    // (f) prefetch next V tile (skip last so kernel ends with vmcnt=0)
    if (it < 31) {
      gld16(gV0, lV0); gld16(gV1, lV1);
      gV0 += 64; gV1 += 64;
    }
  }

  const int b = bh >> 4, h = bh & 15;
#pragma unroll
  for (int mt = 0; mt < 2; ++mt)
#pragma unroll
    for (int r = 0; r < 4; ++r) {
      const int qg = q0 + mt * 16 + quad * 4 + r;
      const float inv = __builtin_amdgcn_rcpf(lacc[mt][r]);
#pragma unroll
      for (int nt = 0; nt < 4; ++nt) {
        const int e = nt * 16 + l15;
        Hc[((size_t)b * 2048 + qg) * 1024 + h * 64 + e] = f2bf(o[mt][nt][r] * inv);
      }
    }
}

extern "C" void kernel_launch(void* const* d_in, const int* in_sizes, int n_in,
                              void* d_out, int out_size, void* d_ws, size_t ws_size,
                              hipStream_t stream) {
  const float* emb = (const float*)d_in[0];
  const float* Wq  = (const float*)d_in[1];
  const float* bq  = (const float*)d_in[2];
  const float* Wk  = (const float*)d_in[3];
  const float* bk  = (const float*)d_in[4];
  const float* Wv  = (const float*)d_in[5];
  const float* bv  = (const float*)d_in[6];
  const float* W1  = (const float*)d_in[7];
  const float* b1  = (const float*)d_in[8];
  const float* W2  = (const float*)d_in[9];
  const float* b2  = (const float*)d_in[10];

  unsigned short* ws = (unsigned short*)d_ws;
  float* out = (float*)d_out;

  cvt_all<<<19465, 256, 0, stream>>>(emb, Wq, bq, Wk, bk, Wv, bv, W1, b1, W2, b2, ws);
  gemm256<2><<<dim3(12, 32), 512, 0, stream>>>(
      ws + EMBB, ws + WQB, ws + WKB, ws + WVB, ws + BQB, ws + BKB, ws + BVB,
      ws + QOFF, ws + KOFF, ws + VTOFF, nullptr, 3072, 1024);
  flash_attn<<<dim3(16, 64), 256, 0, stream>>>(ws + QOFF, ws + KOFF, ws + VTOFF, ws + HCOFF);
  gemm256<1><<<dim3(16, 32), 512, 0, stream>>>(
      ws + HCOFF, ws + W1B, nullptr, nullptr, ws + B1B, nullptr, nullptr,
      ws + HIDOFF, nullptr, nullptr, nullptr, 4096, 1024);
  gemm128<0><<<dim3(8, 64), 256, 0, stream>>>(
      ws + HIDOFF, ws + W2B, nullptr, nullptr, ws + B2B, nullptr, nullptr,
      nullptr, nullptr, nullptr, out, 1024, 4096);
}

// Round 3
// 427.135 us; speedup vs baseline: 1.0203x; 1.0203x over previous
//
#include <hip/hip_runtime.h>
#include <stdint.h>

// ---------------------------------------------------------------------------
// OwnMultiHeadTransformer: B=4, S=2048, D=1024, H=16, HD=64, FF=4096
// fp32 I/O, bf16 MFMA internal.
//   0) cvt_all: fp32 inputs -> bf16 in d_ws
//   1) gemm256<2>: QKV projection (256x256 8-phase); V stored transposed
//   2) flash_attn: no-max exp2 softmax, S^T orientation (R3/R8)
//   3) gemm256<1>: FFN1 + relu (256x256 8-phase)
//   4) gemm128<0>: FFN2 -> d_out (fp32) [N=1024: 256-tile would give only
//      128 blocks = half-idle GPU; keep 128-tile kernel]
// R8: flash_attn issue-early K/V staging + counted vmcnt (97 -> 80.4 us).
// R9: coarse 2-phase gemm256 REGRESSED (113 us, MfmaUtil 17.8%): 1 block/CU
//     with a tile-granular barrier/vmcnt split is latency-exposed (guide
//     m196: coarse split without per-phase interleave HURTS).
// R10: true 8-phase schedule (T3+T4+T5) on the SAME verified gemm256
//     indexing. Per K-tile t (buffer t&1), 4 phases:
//       P1: ds_read af[0-3]k0+bfr[0-3]k0 (8) | stage A0(t+1) | bar,lgkm0,16 MFMA,bar
//       P2: ds_read af[4-7]k0 (4, bfr reuse) | stage A1(t+1) | bar,lgkm0,16 MFMA,bar
//       P3: ds_read af[0-3]k1+bfr[0-3]k1 (8) | stage B1(t+1) | bar,lgkm0,16 MFMA,bar
//       P4: ds_read af[4-7]k1 (4)            | stage B0(t+2) | vmcnt(2),bar,lgkm0,16 MFMA,bar
//     Write-after-read safety: stage targets are regions whose last reader
//     crossed a barrier (A(t-1) free after P4(t-1); B0(t) free after P3(t)).
//     vmcnt(2) (= the 1 half just issued) proves tile t+1 fully landed at
//     the tile boundary; tail uses vmcnt(0) when the t+2 stage is skipped.
// ---------------------------------------------------------------------------

typedef __attribute__((ext_vector_type(8))) short bf16x8;
typedef __attribute__((ext_vector_type(4))) float f32x4;

__device__ __forceinline__ float bf2f(unsigned short u) {
  union { float f; uint32_t i; } v; v.i = ((uint32_t)u) << 16; return v.f;
}
__device__ __forceinline__ unsigned short f2bf(float f) {
  union { float f; uint32_t i; } v; v.f = f;
  uint32_t i = v.i;
  return (unsigned short)((i + 0x7fffu + ((i >> 16) & 1u)) >> 16);  // RNE
}

#if __has_builtin(__builtin_amdgcn_exp2f)
#define EXP2(x) __builtin_amdgcn_exp2f(x)
#else
#define EXP2(x) __expf((x) * 0.6931471805599453f)
#endif

// pack two f32 -> two bf16 (RNE) in one instr; lo gets p0
__device__ __forceinline__ uint32_t cvtpk(float p0, float p1) {
  uint32_t r;
  asm("v_cvt_pk_bf16_f32 %0, %1, %2" : "=v"(r) : "v"(p0), "v"(p1));
  return r;
}

// async 16B global->LDS (wave-uniform base + lane*16 via tid-linear chunks)
__device__ __forceinline__ void gld16(const void* g, void* l) {
  __builtin_amdgcn_global_load_lds(
      (const __attribute__((address_space(1))) uint32_t*)(uintptr_t)g,
      (__attribute__((address_space(3))) uint32_t*)(uintptr_t)l, 16, 0, 0);
}

#define SCALE_Q 0.04508422002778011f  /* log2(e) / sqrt(D=1024) */

// ---- ws layout (bf16 element offsets) -------------------------------------
#define W1B          0
#define W2B    4194304
#define B1B    8388608
#define B2B    8392704
#define BQB    8393728
#define BKB    8394752
#define BVB    8395776
#define EMBB   8396800
#define WQB   16785408
#define WKB   17833984
#define WVB   18882560
#define QOFF  19931136
#define KOFF  28319744
#define VTOFF 36708352
#define HCOFF 45096960        /* peak 53485568 elems = 102 MiB */
#define HIDOFF 8396800        /* hid overlays dead emb/Wqkv regions */

// ---- 0) fp32 -> bf16 ------------------------------------------------------
__global__ void cvt_all(const float* __restrict__ emb, const float* __restrict__ Wq,
                        const float* __restrict__ bq,  const float* __restrict__ Wk,
                        const float* __restrict__ bk,  const float* __restrict__ Wv,
                        const float* __restrict__ bv,  const float* __restrict__ W1,
                        const float* __restrict__ b1,  const float* __restrict__ W2,
                        const float* __restrict__ b2,  unsigned short* __restrict__ ws) {
  const int i4 = blockIdx.x * 256 + threadIdx.x;
  if (i4 >= 4982784) return;
  const float* s; unsigned short* d; int base;
  if      (i4 < 2097152) { s = emb; d = ws + EMBB; base = 0; }
  else if (i4 < 2359296) { s = Wq;  d = ws + WQB;  base = 2097152; }
  else if (i4 < 2621440) { s = Wk;  d = ws + WKB;  base = 2359296; }
  else if (i4 < 2883584) { s = Wv;  d = ws + WVB;  base = 2621440; }
  else if (i4 < 3932160) { s = W1;  d = ws + W1B;  base = 2883584; }
  else if (i4 < 4980736) { s = W2;  d = ws + W2B;  base = 3932160; }
  else if (i4 < 4980992) { s = bq;  d = ws + BQB;  base = 4980736; }
  else if (i4 < 4981248) { s = bk;  d = ws + BKB;  base = 4980992; }
  else if (i4 < 4981504) { s = bv;  d = ws + BVB;  base = 4981248; }
  else if (i4 < 4982528) { s = b1;  d = ws + B1B;  base = 4981504; }
  else                   { s = b2;  d = ws + B2B;  base = 4982528; }
  const int j = i4 - base;
  const float4 v = ((const float4*)s)[j];
  ushort4 o;
  o.x = f2bf(v.x); o.y = f2bf(v.y); o.z = f2bf(v.z); o.w = f2bf(v.w);
  *(ushort4*)(d + (size_t)j * 4) = o;
}

// ---- GEMM 256x256 8-phase: MODE 1 = bias+relu, 2 = QKV routing ------------
// BK=64, 512 threads (8 waves as 2M x 4N), per-wave C = 128x64.
// LDS: A/B double-buffered 256x64 tiles = 128 KiB (1 block/CU, 8 waves).
// Requires M % 256 == 0 (grid supplies 32 row tiles), N % 256, K % 64.
template <int MODE>
__launch_bounds__(512, 2)
__global__ void gemm256(const unsigned short* __restrict__ A,
                        const unsigned short* __restrict__ W0,
                        const unsigned short* __restrict__ W1p,
                        const unsigned short* __restrict__ W2p,
                        const unsigned short* __restrict__ bias0,
                        const unsigned short* __restrict__ bias1,
                        const unsigned short* __restrict__ bias2,
                        unsigned short* __restrict__ out0,
                        unsigned short* __restrict__ out1,
                        unsigned short* __restrict__ out2,
                        float* __restrict__ foutp,
                        int N, int K) {
  __shared__ unsigned short At[2 * 256 * 64];
  __shared__ unsigned short Bt[2 * 256 * 64];
  const int tid  = threadIdx.x;
  const int wave = tid >> 6, lane = tid & 63;
  const int quad = lane >> 4, l15 = lane & 15;
  const int wm = wave >> 2, wn = wave & 3;  // 2 x 4 wave grid

  // XCD swizzle: xcd = lid&7 owns rowTiles == xcd (mod 8); 4 consecutive
  // blocks per xcd share a B col-panel. (bench-verified in R9)
  const int lid = blockIdx.x + blockIdx.y * gridDim.x;
  const int s_ = lid >> 3;
  const int rowBase = (((lid & 7) + ((s_ & 3) << 3)) << 8);  // rowTile*256
  const int colBase = ((s_ >> 2) << 8);                      // colTile*256

  const unsigned short* W = W0;
  const unsigned short* bias = bias0;
  int colW = colBase;
  if (MODE == 2) {
    const int which = colBase >> 10;
    if (which == 1) { W = W1p; bias = bias1; }
    if (which == 2) { W = W2p; bias = bias2; }
    colW = colBase & 1023;
  }

  // Staging: 2048 16B chunks/tile; phys chunk u = row*8 + cc holds logical
  // k-chunk ec = cc ^ (row&7). Half h = chunks [h*1024, h*1024+1024) = rows
  // [h*128, h*128+128). 2 gld16/thread per half.
  const unsigned short* gA[4]; const unsigned short* gB[4];
  unsigned short *lA[4], *lB[4];
#pragma unroll
  for (int i = 0; i < 4; ++i) {
    const int u = tid + 512 * i;  // 0..2047
    const int r = u >> 3, e = (((u & 7) ^ (r & 7)) * 8);
    gA[i] = A + (size_t)(rowBase + r) * K + e;
    gB[i] = W + (size_t)(colW + r) * K + e;
    lA[i] = At + u * 8;
    lB[i] = Bt + u * 8;
  }

#define STAGE_A(h, n) do { const int _i = (h) * 2; const size_t _ko = (size_t)(n) * 64; \
    const int _lo = ((n) & 1) << 14; \
    gld16(gA[_i] + _ko, lA[_i] + _lo); gld16(gA[_i + 1] + _ko, lA[_i + 1] + _lo); } while (0)
#define STAGE_B(h, n) do { const int _i = (h) * 2; const size_t _ko = (size_t)(n) * 64; \
    const int _lo = ((n) & 1) << 14; \
    gld16(gB[_i] + _ko, lB[_i] + _lo); gld16(gB[_i + 1] + _ko, lB[_i + 1] + _lo); } while (0)

  // Fragment offsets (kk=0); kk=1 flips logical-chunk bit 2 -> addr ^ 32.
  int aoff[8], boff[4];
#pragma unroll
  for (int mt = 0; mt < 8; ++mt) {
    const int ra = wm * 128 + mt * 16 + l15;
    aoff[mt] = ra * 64 + ((quad ^ (ra & 7)) * 8);
  }
#pragma unroll
  for (int nt = 0; nt < 4; ++nt) {
    const int rb = wn * 64 + nt * 16 + l15;
    boff[nt] = rb * 64 + ((quad ^ (rb & 7)) * 8);
  }

  const int T = K >> 6;
  // prologue: tile0 (4 halves) + B0(1); tile0 landed, B0(1) in flight
  STAGE_A(0, 0); STAGE_A(1, 0); STAGE_B(0, 0); STAGE_B(1, 0);
  if (T > 1) STAGE_B(0, 1);
  asm volatile("s_waitcnt vmcnt(2)" ::: "memory");
  __builtin_amdgcn_s_barrier();

  f32x4 acc[8][4] = {};
  for (int t = 0; t < T; ++t) {
    const unsigned short* Ab = At + ((t & 1) << 14);
    const unsigned short* Bb = Bt + ((t & 1) << 14);
    bf16x8 af[4], bfr[4];
    // ---- P1: kk0, mt0-3 ----
#pragma unroll
    for (int mt = 0; mt < 4; ++mt) af[mt] = *(const bf16x8*)(Ab + aoff[mt]);
#pragma unroll
    for (int nt = 0; nt < 4; ++nt) bfr[nt] = *(const bf16x8*)(Bb + boff[nt]);
    if (t + 1 < T) STAGE_A(0, t + 1);
    __builtin_amdgcn_s_barrier();
    asm volatile("s_waitcnt lgkmcnt(0)" ::: "memory");
    __builtin_amdgcn_s_setprio(1);
#pragma unroll
    for (int mt = 0; mt < 4; ++mt)
#pragma unroll
      for (int nt = 0; nt < 4; ++nt)
        acc[mt][nt] = __builtin_amdgcn_mfma_f32_16x16x32_bf16(af[mt], bfr[nt], acc[mt][nt], 0, 0, 0);
    __builtin_amdgcn_s_setprio(0);
    __builtin_amdgcn_s_barrier();
    // ---- P2: kk0, mt4-7 (bfr reuse) ----
#pragma unroll
    for (int mt = 0; mt < 4; ++mt) af[mt] = *(const bf16x8*)(Ab + aoff[mt + 4]);
    if (t + 1 < T) STAGE_A(1, t + 1);
    __builtin_amdgcn_s_barrier();
    asm volatile("s_waitcnt lgkmcnt(0)" ::: "memory");
    __builtin_amdgcn_s_setprio(1);
#pragma unroll
    for (int mt = 0; mt < 4; ++mt)
#pragma unroll
      for (int nt = 0; nt < 4; ++nt)
        acc[mt + 4][nt] = __builtin_amdgcn_mfma_f32_16x16x32_bf16(af[mt], bfr[nt], acc[mt + 4][nt], 0, 0, 0);
    __builtin_amdgcn_s_setprio(0);
    __builtin_amdgcn_s_barrier();
    // ---- P3: kk1, mt0-3 ----
#pragma unroll
    for (int mt = 0; mt < 4; ++mt) af[mt] = *(const bf16x8*)(Ab + (aoff[mt] ^ 32));
#pragma unroll
    for (int nt = 0; nt < 4; ++nt) bfr[nt] = *(const bf16x8*)(Bb + (boff[nt] ^ 32));
    if (t + 1 < T) STAGE_B(1, t + 1);
    __builtin_amdgcn_s_barrier();
    asm volatile("s_waitcnt lgkmcnt(0)" ::: "memory");
    __builtin_amdgcn_s_setprio(1);
#pragma unroll
    for (int mt = 0; mt < 4; ++mt)
#pragma unroll
      for (int nt = 0; nt < 4; ++nt)
        acc[mt][nt] = __builtin_amdgcn_mfma_f32_16x16x32_bf16(af[mt], bfr[nt], acc[mt][nt], 0, 0, 0);
    __builtin_amdgcn_s_setprio(0);
    __builtin_amdgcn_s_barrier();
    // ---- P4: kk1, mt4-7 ----
#pragma unroll
    for (int mt = 0; mt < 4; ++mt) af[mt] = *(const bf16x8*)(Ab + (aoff[mt + 4] ^ 32));
    if (t + 2 < T) {
      STAGE_B(0, t + 2);
      asm volatile("s_waitcnt vmcnt(2)" ::: "memory");  // tile t+1 fully landed
    } else {
      asm volatile("s_waitcnt vmcnt(0)" ::: "memory");  // tail: force last halves
    }
    __builtin_amdgcn_s_barrier();
    asm volatile("s_waitcnt lgkmcnt(0)" ::: "memory");
    __builtin_amdgcn_s_setprio(1);
#pragma unroll
    for (int mt = 0; mt < 4; ++mt)
#pragma unroll
      for (int nt = 0; nt < 4; ++nt)
        acc[mt + 4][nt] = __builtin_amdgcn_mfma_f32_16x16x32_bf16(af[mt], bfr[nt], acc[mt + 4][nt], 0, 0, 0);
    __builtin_amdgcn_s_setprio(0);
    __builtin_amdgcn_s_barrier();
  }
  asm volatile("s_waitcnt vmcnt(0)" ::: "memory");
#undef STAGE_A
#undef STAGE_B

#pragma unroll
  for (int mt = 0; mt < 8; ++mt) {
    const int row = rowBase + wm * 128 + mt * 16 + quad * 4;
#pragma unroll
    for (int nt = 0; nt < 4; ++nt) {
      const int cIn = colW + wn * 64 + nt * 16 + l15;
      const float bv = bf2f(bias[cIn]);
      if (MODE == 2) {
        const int which = colBase >> 10;
        const int h = cIn >> 6, e = cIn & 63;
#pragma unroll
        for (int r = 0; r < 4; ++r) {
          const int tok = row + r;
          const int b = tok >> 11, s = tok & 2047;
          const float v = acc[mt][nt][r] + bv;
          const size_t bh = (size_t)(b * 16 + h);
          if (which == 0)      out0[(bh * 2048 + s) * 64 + e] = f2bf(v * SCALE_Q);
          else if (which == 1) out1[(bh * 2048 + s) * 64 + e] = f2bf(v);
          else                 out2[(bh * 64 + e) * 2048 + s] = f2bf(v);  // V^T
        }
      } else if (MODE == 1) {
#pragma unroll
        for (int r = 0; r < 4; ++r) {
          const float v = fmaxf(acc[mt][nt][r] + bv, 0.0f);
          out0[(size_t)(row + r) * N + cIn] = f2bf(v);
        }
      } else {
#pragma unroll
        for (int r = 0; r < 4; ++r)
          foutp[(size_t)(row + r) * N + cIn] = acc[mt][nt][r] + bv;
      }
    }
  }
}

// ---- GEMM 128x128 (kept for FFN2: N=1024 -> 512 blocks at this tile) ------
template <int MODE>
__launch_bounds__(256, 4)
__global__ void gemm128(const unsigned short* __restrict__ A,
                        const unsigned short* __restrict__ W0,
                        const unsigned short* __restrict__ W1p,
                        const unsigned short* __restrict__ W2p,
                        const unsigned short* __restrict__ bias0,
                        const unsigned short* __restrict__ bias1,
                        const unsigned short* __restrict__ bias2,
                        unsigned short* __restrict__ out0,
                        unsigned short* __restrict__ out1,
                        unsigned short* __restrict__ out2,
                        float* __restrict__ foutp,
                        int N, int K) {
  __shared__ unsigned short At[128 * 64];
  __shared__ unsigned short Bt[128 * 64];
  const int tid  = threadIdx.x;
  const int wave = tid >> 6, lane = tid & 63;
  const int quad = lane >> 4, l15 = lane & 15;

  const int lid = blockIdx.x + blockIdx.y * gridDim.x;
  const int s_ = lid >> 3;
  const int rowBase = (((lid & 7) + ((s_ & 7) << 3)) << 7);
  const int colBase = ((s_ >> 3) << 7);

  const unsigned short* W = W0;
  const unsigned short* bias = bias0;
  int colW = colBase;
  if (MODE == 2) {
    const int which = colBase >> 10;
    if (which == 1) { W = W1p; bias = bias1; }
    if (which == 2) { W = W2p; bias = bias2; }
    colW = colBase & 1023;
  }

  const unsigned short* gA[4]; const unsigned short* gB[4];
  unsigned short *lA[4], *lB[4];
#pragma unroll
  for (int i = 0; i < 4; ++i) {
    const int u = tid + 256 * i;
    const int r = u >> 3, e = (((u & 7) ^ (r & 7)) * 8);
    gA[i] = A + (size_t)(rowBase + r) * K + e;
    gB[i] = W + (size_t)(colW + r) * K + e;
    lA[i] = At + u * 8;
    lB[i] = Bt + u * 8;
  }

  const int wrow = (wave & 1) * 64, wcol = (wave >> 1) * 64;
  int aoff[2][4], boff[2][4];
#pragma unroll
  for (int kk = 0; kk < 2; ++kk)
#pragma unroll
    for (int t = 0; t < 4; ++t) {
      const int ra = wrow + t * 16 + l15;
      aoff[kk][t] = ra * 64 + (((quad + 4 * kk) ^ (ra & 7)) * 8);
      const int rb = wcol + t * 16 + l15;
      boff[kk][t] = rb * 64 + (((quad + 4 * kk) ^ (rb & 7)) * 8);
    }

  f32x4 acc[4][4] = {};
  for (int k0 = 0; k0 < K; k0 += 64) {
    __syncthreads();
#pragma unroll
    for (int i = 0; i < 4; ++i) { gld16(gA[i], lA[i]); gld16(gB[i], lB[i]); }
#pragma unroll
    for (int i = 0; i < 4; ++i) { gA[i] += 64; gB[i] += 64; }
    __syncthreads();
#pragma unroll
    for (int kk = 0; kk < 2; ++kk) {
      bf16x8 af[4], bfr[4];
#pragma unroll
      for (int t = 0; t < 4; ++t) af[t]  = *(const bf16x8*)(At + aoff[kk][t]);
#pragma unroll
      for (int t = 0; t < 4; ++t) bfr[t] = *(const bf16x8*)(Bt + boff[kk][t]);
#pragma unroll
      for (int mt = 0; mt < 4; ++mt)
#pragma unroll
        for (int nt = 0; nt < 4; ++nt)
          acc[mt][nt] = __builtin_amdgcn_mfma_f32_16x16x32_bf16(
              af[mt], bfr[nt], acc[mt][nt], 0, 0, 0);
    }
  }

#pragma unroll
  for (int mt = 0; mt < 4; ++mt) {
    const int row = rowBase + wrow + mt * 16 + quad * 4;
#pragma unroll
    for (int nt = 0; nt < 4; ++nt) {
      const int cIn = colW + wcol + nt * 16 + l15;
      const float bv = bf2f(bias[cIn]);
      if (MODE == 2) {
        const int which = colBase >> 10;
        const int h = cIn >> 6, e = cIn & 63;
#pragma unroll
        for (int r = 0; r < 4; ++r) {
          const int tok = row + r;
          const int b = tok >> 11, s = tok & 2047;
          const float v = acc[mt][nt][r] + bv;
          const size_t bh = (size_t)(b * 16 + h);
          if (which == 0)      out0[(bh * 2048 + s) * 64 + e] = f2bf(v * SCALE_Q);
          else if (which == 1) out1[(bh * 2048 + s) * 64 + e] = f2bf(v);
          else                 out2[(bh * 64 + e) * 2048 + s] = f2bf(v);  // V^T
        }
      } else if (MODE == 1) {
#pragma unroll
        for (int r = 0; r < 4; ++r) {
          const float v = fmaxf(acc[mt][nt][r] + bv, 0.0f);
          out0[(size_t)(row + r) * N + cIn] = f2bf(v);
        }
      } else {
#pragma unroll
        for (int r = 0; r < 4; ++r)
          foutp[(size_t)(row + r) * N + cIn] = acc[mt][nt][r] + bv;
      }
    }
  }
}

// ---- flash attention (R3/R8): S^T orientation, no-max exp2 softmax --------
// grid (16, 64): logical (q-block, b*16+h); XCD-swizzled.
__launch_bounds__(256, 4)
__global__ void flash_attn(const unsigned short* __restrict__ Q,
                           const unsigned short* __restrict__ Kg,
                           const unsigned short* __restrict__ Vt,
                           unsigned short* __restrict__ Hc) {
  __shared__ unsigned short Kt[2 * 64 * 64];  // K tile dbuf [t][e], chunk-swizzled
  __shared__ unsigned short Vs[64 * 64];      // V^T tile [e][t], chunk-swizzled
  __shared__ unsigned short Pl[4][32 * 64];   // per-wave P [q][t], chunk-swizzled
  const int tid  = threadIdx.x;
  const int wave = tid >> 6, lane = tid & 63;
  const int quad = lane >> 4, l15 = lane & 15;

  const int lid = blockIdx.x + blockIdx.y * gridDim.x;
  const int s_ = lid >> 3;
  const int bh = (lid & 7) + ((s_ & 7) << 3);
  const int q0 = ((s_ >> 3) << 7) + wave * 32;

  const size_t base = (size_t)bh * (2048 * 64);
  const unsigned short* Qb = Q  + base;
  const unsigned short* Kb = Kg + base;
  const unsigned short* Vb = Vt + base;   // [64 e][2048 t]

  bf16x8 qf[2][2];
#pragma unroll
  for (int qt = 0; qt < 2; ++qt) {
    const int q = q0 + qt * 16 + l15;
#pragma unroll
    for (int kk = 0; kk < 2; ++kk)
      qf[qt][kk] = *(const bf16x8*)(Qb + (size_t)q * 64 + kk * 32 + quad * 8);
  }

  const int u0 = tid, u1 = tid + 256;
  const int kr0 = u0 >> 3, kc0 = (((u0 & 7) ^ (kr0 & 7)) * 8);
  const int kr1 = u1 >> 3, kc1 = (((u1 & 7) ^ (kr1 & 7)) * 8);
  const unsigned short* gK0 = Kb + (size_t)kr0 * 64 + kc0;
  const unsigned short* gK1 = Kb + (size_t)kr1 * 64 + kc1;
  const unsigned short* gV0 = Vb + (size_t)kr0 * 2048 + kc0;
  const unsigned short* gV1 = Vb + (size_t)kr1 * 2048 + kc1;
  unsigned short* lK0 = Kt + u0 * 8;
  unsigned short* lK1 = Kt + u1 * 8;
  unsigned short* lV0 = Vs + u0 * 8;
  unsigned short* lV1 = Vs + u1 * 8;

  // prologue: tile 0 into Kt[0] / Vs, full drain
  gld16(gK0, lK0); gld16(gK1, lK1);
  gld16(gV0, lV0); gld16(gV1, lV1);
  gK0 += 4096; gK1 += 4096; gV0 += 64; gV1 += 64;
  __syncthreads();

  const short oneb = (short)0x3F80;  // bf16 1.0
  const bf16x8 ones = {oneb, oneb, oneb, oneb, oneb, oneb, oneb, oneb};
  f32x4 o[2][4] = {};
  f32x4 lacc[2] = {};
  unsigned short* Pw = Pl[wave];

  for (int it = 0; it < 32; ++it) {
    const int nb = ((it + 1) & 1) * 4096;
    // (a) prefetch next K tile into the other buffer
    gld16(gK0, lK0 + nb); gld16(gK1, lK1 + nb);
    gK0 += 4096; gK1 += 4096;

    const unsigned short* Kc = Kt + (it & 1) * 4096;

    // (b) S^T = K Q^T
    f32x4 st[4][2] = {};
    __builtin_amdgcn_s_setprio(1);
#pragma unroll
    for (int tt = 0; tt < 4; ++tt) {
      const int t = tt * 16 + l15;
      const bf16x8 kf0 = *(const bf16x8*)(Kc + t * 64 + ((quad       ^ (t & 7)) * 8));
      const bf16x8 kf1 = *(const bf16x8*)(Kc + t * 64 + (((quad + 4) ^ (t & 7)) * 8));
#pragma unroll
      for (int qt = 0; qt < 2; ++qt) {
        st[tt][qt] = __builtin_amdgcn_mfma_f32_16x16x32_bf16(kf0, qf[qt][0], st[tt][qt], 0, 0, 0);
        st[tt][qt] = __builtin_amdgcn_mfma_f32_16x16x32_bf16(kf1, qf[qt][1], st[tt][qt], 0, 0, 0);
      }
    }
    __builtin_amdgcn_s_setprio(0);

    // p = exp2(s), pack -> P[q][t] LDS (per-wave)
#pragma unroll
    for (int tt = 0; tt < 4; ++tt) {
      const int tc = tt * 2 + (quad >> 1);
#pragma unroll
      for (int qt = 0; qt < 2; ++qt) {
        const float p0 = EXP2(st[tt][qt][0]);
        const float p1 = EXP2(st[tt][qt][1]);
        const float p2 = EXP2(st[tt][qt][2]);
        const float p3 = EXP2(st[tt][qt][3]);
        uint2 w;
        w.x = cvtpk(p0, p1);
        w.y = cvtpk(p2, p3);
        const int qrow = qt * 16 + l15;
        *(uint2*)(Pw + qrow * 64 + ((tc ^ (qrow & 7)) * 8) + (quad & 1) * 4) = w;
      }
    }

    // (c) own V(it) landed (K(it+1) stays in flight), then all-waves barrier
    asm volatile("s_waitcnt vmcnt(2)" ::: "memory");
    __builtin_amdgcn_s_barrier();

    // (d) O += P V ; l += P * 1
    bf16x8 pf[2][2];
#pragma unroll
    for (int mt = 0; mt < 2; ++mt) {
      const int qq = mt * 16 + l15;
      pf[mt][0] = *(const bf16x8*)(Pw + qq * 64 + ((quad       ^ (qq & 7)) * 8));
      pf[mt][1] = *(const bf16x8*)(Pw + qq * 64 + (((quad + 4) ^ (qq & 7)) * 8));
    }
    __builtin_amdgcn_s_setprio(1);
#pragma unroll
    for (int nt = 0; nt < 4; ++nt) {
      const int e = nt * 16 + l15;
      const bf16x8 vf0 = *(const bf16x8*)(Vs + e * 64 + ((quad       ^ (e & 7)) * 8));
      const bf16x8 vf1 = *(const bf16x8*)(Vs + e * 64 + (((quad + 4) ^ (e & 7)) * 8));
#pragma unroll
      for (int mt = 0; mt < 2; ++mt) {
        o[mt][nt] = __builtin_amdgcn_mfma_f32_16x16x32_bf16(pf[mt][0], vf0, o[mt][nt], 0, 0, 0);
        o[mt][nt] = __builtin_amdgcn_mfma_f32_16x16x32_bf16(pf[mt][1], vf1, o[mt][nt], 0, 0, 0);
      }
    }
#pragma unroll
    for (int mt = 0; mt < 2; ++mt) {
      lacc[mt] = __builtin_amdgcn_mfma_f32_16x16x32_bf16(pf[mt][0], ones, lacc[mt], 0, 0, 0);
      lacc[mt] = __builtin_amdgcn_mfma_f32_16x16x32_bf16(pf[mt][1], ones, lacc[mt], 0, 0, 0);
    }
    __builtin_amdgcn_s_setprio(0);

    // (e) own K(it+1) landed + all waves done reading Vs
    asm volatile("s_waitcnt vmcnt(0)" ::: "memory");
    __builtin_amdgcn_s_barrier();

    // (f) prefetch next V tile (skip last so kernel ends with vmcnt=0)
    if (it < 31) {
      gld16(gV0, lV0); gld16(gV1, lV1);
      gV0 += 64; gV1 += 64;
    }
  }

  const int b = bh >> 4, h = bh & 15;
#pragma unroll
  for (int mt = 0; mt < 2; ++mt)
#pragma unroll
    for (int r = 0; r < 4; ++r) {
      const int qg = q0 + mt * 16 + quad * 4 + r;
      const float inv = __builtin_amdgcn_rcpf(lacc[mt][r]);
#pragma unroll
      for (int nt = 0; nt < 4; ++nt) {
        const int e = nt * 16 + l15;
        Hc[((size_t)b * 2048 + qg) * 1024 + h * 64 + e] = f2bf(o[mt][nt][r] * inv);
      }
    }
}

extern "C" void kernel_launch(void* const* d_in, const int* in_sizes, int n_in,
                              void* d_out, int out_size, void* d_ws, size_t ws_size,
                              hipStream_t stream) {
  const float* emb = (const float*)d_in[0];
  const float* Wq  = (const float*)d_in[1];
  const float* bq  = (const float*)d_in[2];
  const float* Wk  = (const float*)d_in[3];
  const float* bk  = (const float*)d_in[4];
  const float* Wv  = (const float*)d_in[5];
  const float* bv  = (const float*)d_in[6];
  const float* W1  = (const float*)d_in[7];
  const float* b1  = (const float*)d_in[8];
  const float* W2  = (const float*)d_in[9];
  const float* b2  = (const float*)d_in[10];

  unsigned short* ws = (unsigned short*)d_ws;
  float* out = (float*)d_out;

  cvt_all<<<19465, 256, 0, stream>>>(emb, Wq, bq, Wk, bk, Wv, bv, W1, b1, W2, b2, ws);
  gemm256<2><<<dim3(12, 32), 512, 0, stream>>>(
      ws + EMBB, ws + WQB, ws + WKB, ws + WVB, ws + BQB, ws + BKB, ws + BVB,
      ws + QOFF, ws + KOFF, ws + VTOFF, nullptr, 3072, 1024);
  flash_attn<<<dim3(16, 64), 256, 0, stream>>>(ws + QOFF, ws + KOFF, ws + VTOFF, ws + HCOFF);
  gemm256<1><<<dim3(16, 32), 512, 0, stream>>>(
      ws + HCOFF, ws + W1B, nullptr, nullptr, ws + B1B, nullptr, nullptr,
      ws + HIDOFF, nullptr, nullptr, nullptr, 4096, 1024);
  gemm128<0><<<dim3(8, 64), 256, 0, stream>>>(
      ws + HIDOFF, ws + W2B, nullptr, nullptr, ws + B2B, nullptr, nullptr,
      nullptr, nullptr, nullptr, out, 1024, 4096);
}